// Round 3
// baseline (1108.037 us; speedup 1.0000x reference)
//
#include <hip/hip_runtime.h>

typedef unsigned int u32;
typedef unsigned short u16;
typedef unsigned long long u64;

typedef __attribute__((ext_vector_type(8))) short s8v;   // 8 bf16 (4 VGPRs)
typedef __attribute__((ext_vector_type(4))) float f4v;   // 4 fp32 acc

#define B_SZ   8192
#define V_SZ   1000
#define KCH    5
#define MAXDEG 32

__device__ __forceinline__ u16 f2bf(float f) {
    u32 u = __float_as_uint(f);
    u32 r = (u + 0x7FFFu + ((u >> 16) & 1u)) >> 16;   // RNE
    return (u16)r;
}
__device__ __forceinline__ float bf2f(u16 h) { return __uint_as_float(((u32)h) << 16); }

// ---------------------------------------------------------------------------
// K0: build packed sparse Lr (off-diag) + diagonal. One wave per row.
// TRANSPOSED layout: packed4[q4*V + v] is an int4 holding entries 4q4..4q4+3
// of row v -> k_cheby's per-lane loads (consecutive v) are fully coalesced.
// entry: (fp32 weight, low 10 mantissa bits cleared) | col (10 bits); tail = 0.
// ---------------------------------------------------------------------------
__global__ __launch_bounds__(256) void k_build(const float* __restrict__ L,
                                               const float* __restrict__ lmax,
                                               u32* __restrict__ packed,   // [8][V][4] u32
                                               int* __restrict__ cnts,
                                               float* __restrict__ diagw) {
    int wid  = threadIdx.x >> 6;
    int lane = threadIdx.x & 63;
    int row  = blockIdx.x * 4 + wid;
    if (row >= V_SZ) return;
    float s = 2.0f / lmax[0];
    const float* Lrow = L + (u64)row * V_SZ;
    int cnt = 0;
    for (int c0 = 0; c0 < V_SZ; c0 += 64) {
        int c = c0 + lane;
        float val = 0.0f;
        if (c < V_SZ && c != row) val = Lrow[c];
        bool nz = (val != 0.0f);
        u64 m = __ballot(nz);
        int pos = cnt + __popcll(m & ((1ull << lane) - 1ull));
        if (nz && pos < MAXDEG) {
            u32 w = __float_as_uint(val * s);
            packed[((pos >> 2) * V_SZ + row) * 4 + (pos & 3)] = (w & 0xFFFFFC00u) | (u32)c;
        }
        cnt += __popcll(m);
    }
    int cc = cnt < MAXDEG ? cnt : MAXDEG;
    for (int e = cc + lane; e < MAXDEG; e += 64)
        packed[((e >> 2) * V_SZ + row) * 4 + (e & 3)] = 0;
    if (lane == 0) {
        cnts[row]  = cc;
        diagw[row] = s * Lrow[row] - 1.0f;
    }
}

// ---------------------------------------------------------------------------
// Kpre: weight conversions to bf16 (+K padding) and folded BN affine params.
// ---------------------------------------------------------------------------
__global__ __launch_bounds__(256) void k_pre(const float* __restrict__ fc1W,
                                             const float* __restrict__ lin1W,
                                             const float* __restrict__ gam,
                                             const float* __restrict__ bet,
                                             const float* __restrict__ mea,
                                             const float* __restrict__ var,
                                             u16* __restrict__ fc1w_b,
                                             u16* __restrict__ lin1w_b,
                                             float* __restrict__ bn_a,
                                             float* __restrict__ bn_c) {
    int t = blockIdx.x * 256 + threadIdx.x;
    if (t < 256 * 640) {
        int r = t / 640, c = t - r * 640;
        fc1w_b[t] = (c < 625) ? f2bf(fc1W[r * 625 + c]) : (u16)0;
    }
    if (t < 256 * 256) lin1w_b[t] = f2bf(lin1W[t]);
    if (t < 4 * 256) {
        float a = gam[t] * rsqrtf(var[t] + 1e-5f);
        bn_a[t] = a;
        bn_c[t] = bet[t] - mea[t] * a;
    }
}

// ---------------------------------------------------------------------------
// K1: fused Chebyshev recursion + cl1 + ReLU + maxpool8 -> bf16
// 512 threads, 2 rows/thread, 2 batch cols/block.
// Ping-pong 2 LDS stage buffers (16 KB): stage k gathers read only x_{k-1};
// x_{k-2}[v] is read only by its owner thread before in-place overwrite.
// Quad-0 of each row's sparse structure kept in registers (stage-invariant).
// ---------------------------------------------------------------------------
__global__ __launch_bounds__(512, 8) void k_cheby(const float* __restrict__ x,
                                                  const int4* __restrict__ packed4,
                                                  const int* __restrict__ cnts,
                                                  const float* __restrict__ diagw,
                                                  const float* __restrict__ cl1W,
                                                  const float* __restrict__ cl1b,
                                                  u16* __restrict__ pooled) {
    __shared__ float buf[2][V_SZ * 2];   // [pingpong][v*2 + b] = 16 KB
    __shared__ float cws[25];
    __shared__ float cbs[5];
    int t  = threadIdx.x;
    int b0 = blockIdx.x * 2;

    if (t < 25) cws[t] = cl1W[t];
    if (t < 5)  cbs[t] = cl1b[t];

    const int  v1   = t + 512;
    const bool val1 = (v1 < V_SZ);

    float d0 = diagw[t];
    int   n0 = (cnts[t] + 3) >> 2;
    float d1 = 0.f;
    int   n1 = 0;
    if (val1) { d1 = diagw[v1]; n1 = (cnts[v1] + 3) >> 2; }

    // stage 0 staging: buf[0][v] = (x[b0][v], x[b0+1][v])
    float2 x00, x01;
    x00.x = x[(u64)b0 * V_SZ + t];
    x00.y = x[(u64)(b0 + 1) * V_SZ + t];
    ((float2*)buf[0])[t] = x00;
    x01 = make_float2(0.f, 0.f);
    if (val1) {
        x01.x = x[(u64)b0 * V_SZ + v1];
        x01.y = x[(u64)(b0 + 1) * V_SZ + v1];
        ((float2*)buf[0])[v1] = x01;
    }
    int4 pf0 = packed4[t];                                   // quad 0, row t
    int4 pf1 = val1 ? packed4[v1] : make_int4(0, 0, 0, 0);   // quad 0, row v1
    __syncthreads();

    // feat init with k=0 term
    float2 feat0[5], feat1[5];
#pragma unroll
    for (int f = 0; f < 5; ++f) {
        float w = cws[f * 5];
        feat0[f] = make_float2(w * x00.x, w * x00.y);
        feat1[f] = make_float2(w * x01.x, w * x01.y);
    }

    // stages 1..4
    for (int k = 1; k < KCH; ++k) {
        const float2* prev = (const float2*)buf[(k - 1) & 1];
        float2*       curb = (float2*)buf[k & 1];

        // ---- row 0 (v = t) ----
        {
            float2 pv = prev[t];
            float a0 = d0 * pv.x, a1 = d0 * pv.y;
            int4 pw = pf0;
            int  q  = 0;
            while (true) {
                float2 g0 = prev[(u32)pw.x & 1023u];
                float2 g1 = prev[(u32)pw.y & 1023u];
                float2 g2 = prev[(u32)pw.z & 1023u];
                float2 g3 = prev[(u32)pw.w & 1023u];
                float w0 = __uint_as_float((u32)pw.x & 0xFFFFFC00u);
                float w1 = __uint_as_float((u32)pw.y & 0xFFFFFC00u);
                float w2 = __uint_as_float((u32)pw.z & 0xFFFFFC00u);
                float w3 = __uint_as_float((u32)pw.w & 0xFFFFFC00u);
                a0 = fmaf(w0, g0.x, a0); a1 = fmaf(w0, g0.y, a1);
                a0 = fmaf(w1, g1.x, a0); a1 = fmaf(w1, g1.y, a1);
                a0 = fmaf(w2, g2.x, a0); a1 = fmaf(w2, g2.y, a1);
                a0 = fmaf(w3, g3.x, a0); a1 = fmaf(w3, g3.y, a1);
                if (++q >= n0) break;
                pw = packed4[q * V_SZ + t];                  // coalesced
            }
            if (k >= 2) {
                float2 m2 = curb[t];
                a0 = 2.0f * a0 - m2.x;
                a1 = 2.0f * a1 - m2.y;
            }
            curb[t] = make_float2(a0, a1);
#pragma unroll
            for (int f = 0; f < 5; ++f) {
                float w = cws[f * 5 + k];
                feat0[f].x = fmaf(w, a0, feat0[f].x);
                feat0[f].y = fmaf(w, a1, feat0[f].y);
            }
        }
        // ---- row 1 (v = t + 512) ----
        if (val1) {
            float2 pv = prev[v1];
            float a0 = d1 * pv.x, a1 = d1 * pv.y;
            int4 pw = pf1;
            int  q  = 0;
            while (true) {
                float2 g0 = prev[(u32)pw.x & 1023u];
                float2 g1 = prev[(u32)pw.y & 1023u];
                float2 g2 = prev[(u32)pw.z & 1023u];
                float2 g3 = prev[(u32)pw.w & 1023u];
                float w0 = __uint_as_float((u32)pw.x & 0xFFFFFC00u);
                float w1 = __uint_as_float((u32)pw.y & 0xFFFFFC00u);
                float w2 = __uint_as_float((u32)pw.z & 0xFFFFFC00u);
                float w3 = __uint_as_float((u32)pw.w & 0xFFFFFC00u);
                a0 = fmaf(w0, g0.x, a0); a1 = fmaf(w0, g0.y, a1);
                a0 = fmaf(w1, g1.x, a0); a1 = fmaf(w1, g1.y, a1);
                a0 = fmaf(w2, g2.x, a0); a1 = fmaf(w2, g2.y, a1);
                a0 = fmaf(w3, g3.x, a0); a1 = fmaf(w3, g3.y, a1);
                if (++q >= n1) break;
                pw = packed4[q * V_SZ + v1];
            }
            if (k >= 2) {
                float2 m2 = curb[v1];
                a0 = 2.0f * a0 - m2.x;
                a1 = 2.0f * a1 - m2.y;
            }
            curb[v1] = make_float2(a0, a1);
#pragma unroll
            for (int f = 0; f < 5; ++f) {
                float w = cws[f * 5 + k];
                feat1[f].x = fmaf(w, a0, feat1[f].x);
                feat1[f].y = fmaf(w, a1, feat1[f].y);
            }
        }
        __syncthreads();
    }

    // bias + ReLU + maxpool8 via 8-lane shuffle (8 consecutive v per group)
#pragma unroll
    for (int f = 0; f < 5; ++f) {
#pragma unroll
        for (int b = 0; b < 2; ++b) {
            float s0 = fmaxf((b ? feat0[f].y : feat0[f].x) + cbs[f], 0.0f);
            s0 = fmaxf(s0, __shfl_xor(s0, 1));
            s0 = fmaxf(s0, __shfl_xor(s0, 2));
            s0 = fmaxf(s0, __shfl_xor(s0, 4));
            if ((t & 7) == 0)
                pooled[(u64)(b0 + b) * 640 + (t >> 3) * 5 + f] = f2bf(s0);

            float s1 = val1 ? fmaxf((b ? feat1[f].y : feat1[f].x) + cbs[f], 0.0f) : 0.0f;
            s1 = fmaxf(s1, __shfl_xor(s1, 1));
            s1 = fmaxf(s1, __shfl_xor(s1, 2));
            s1 = fmaxf(s1, __shfl_xor(s1, 4));
            if ((t & 7) == 0 && val1)
                pooled[(u64)(b0 + b) * 640 + (v1 >> 3) * 5 + f] = f2bf(s1);
        }
    }
    // zero the K-padding columns 625..639
    if (t < 30) {
        int b = t / 15, c = 625 + (t % 15);
        pooled[(u64)(b0 + b) * 640 + c] = 0;
    }
}

// ---------------------------------------------------------------------------
// K2/K3: bf16 MFMA GEMM, C[m][n] = sum_k A[m][k]*Bw[n][k] (+epilogue)
// BM=128 BN=64 BK=64, 256 thr (4 waves), wave = 32x64 out = 2x4 MFMA tiles.
// MODE 0: + fc1 bias, BN x4 folded affine + relu, JK max  -> bf16
// MODE 1: + lin1 bias, relu                                -> bf16
// ---------------------------------------------------------------------------
template <int MODE>
__global__ __launch_bounds__(256) void k_gemm(const u16* __restrict__ A,
                                              const u16* __restrict__ Bw,
                                              int Kdim,
                                              const float* __restrict__ bias,
                                              const float* __restrict__ bn_a,
                                              const float* __restrict__ bn_c,
                                              u16* __restrict__ Cout) {
    __shared__ u16 As[128][72];   // +8 pad: row stride 36 dw -> 2-way (free)
    __shared__ u16 Bs[64][72];
    int t    = threadIdx.x;
    int lane = t & 63;
    int wid  = t >> 6;
    int m0   = blockIdx.x * 128;
    int n0   = blockIdx.y * 64;

    f4v acc[2][4];
#pragma unroll
    for (int i = 0; i < 2; ++i)
#pragma unroll
        for (int j = 0; j < 4; ++j) acc[i][j] = (f4v){0.f, 0.f, 0.f, 0.f};

    for (int k0 = 0; k0 < Kdim; k0 += 64) {
        int4 ra[4], rb[2];
#pragma unroll
        for (int i = 0; i < 4; ++i) {
            int c = t + i * 256, row = c >> 3, kc = c & 7;
            ra[i] = *(const int4*)(A + (u64)(m0 + row) * Kdim + k0 + kc * 8);
        }
#pragma unroll
        for (int i = 0; i < 2; ++i) {
            int c = t + i * 256, row = c >> 3, kc = c & 7;
            rb[i] = *(const int4*)(Bw + (u64)(n0 + row) * Kdim + k0 + kc * 8);
        }
        __syncthreads();   // prior iter's LDS reads done
#pragma unroll
        for (int i = 0; i < 4; ++i) {
            int c = t + i * 256, row = c >> 3, kc = c & 7;
            *(int4*)(&As[row][kc * 8]) = ra[i];
        }
#pragma unroll
        for (int i = 0; i < 2; ++i) {
            int c = t + i * 256, row = c >> 3, kc = c & 7;
            *(int4*)(&Bs[row][kc * 8]) = rb[i];
        }
        __syncthreads();
#pragma unroll
        for (int ks = 0; ks < 2; ++ks) {
            int kq = ks * 32 + (lane >> 4) * 8;
            s8v af[2], bf[4];
#pragma unroll
            for (int mt = 0; mt < 2; ++mt) {
                int rl = wid * 32 + mt * 16 + (lane & 15);
                af[mt] = *(const s8v*)(&As[rl][kq]);
            }
#pragma unroll
            for (int nt = 0; nt < 4; ++nt) {
                int cl = nt * 16 + (lane & 15);
                bf[nt] = *(const s8v*)(&Bs[cl][kq]);
            }
#pragma unroll
            for (int mt = 0; mt < 2; ++mt)
#pragma unroll
                for (int nt = 0; nt < 4; ++nt)
                    acc[mt][nt] = __builtin_amdgcn_mfma_f32_16x16x32_bf16(
                        af[mt], bf[nt], acc[mt][nt], 0, 0, 0);
        }
    }

    // epilogue: C/D layout col=lane&15, row=(lane>>4)*4+reg  [m89-verified]
#pragma unroll
    for (int nt = 0; nt < 4; ++nt) {
        int col = n0 + nt * 16 + (lane & 15);
        float bv = bias[col];
        float a_[4], c_[4];
        if (MODE == 0) {
#pragma unroll
            for (int i = 0; i < 4; ++i) {
                a_[i] = bn_a[i * 256 + col];
                c_[i] = bn_c[i * 256 + col];
            }
        }
#pragma unroll
        for (int mt = 0; mt < 2; ++mt) {
            int rbase = m0 + wid * 32 + mt * 16 + (lane >> 4) * 4;
#pragma unroll
            for (int r = 0; r < 4; ++r) {
                float v = acc[mt][nt][r] + bv;
                if (MODE == 0) {
                    float h = v, z = 0.0f;
#pragma unroll
                    for (int i = 0; i < 4; ++i) {
                        h = fmaxf(fmaf(a_[i], h, c_[i]), 0.0f);
                        z = fmaxf(z, h);
                    }
                    v = z;
                } else {
                    v = fmaxf(v, 0.0f);
                }
                Cout[(u64)(rbase + r) * 256 + col] = f2bf(v);
            }
        }
    }
}

// ---------------------------------------------------------------------------
// K4: lin2 ([8192,256]@[10,256]^T + b) + log_softmax -> fp32 out
// 64 rows per block, rows staged in LDS (stride 129 dw: conflict-free).
// ---------------------------------------------------------------------------
__global__ __launch_bounds__(256) void k_lin2(const u16* __restrict__ z2,
                                              const float* __restrict__ W2,
                                              const float* __restrict__ b2,
                                              float* __restrict__ out) {
    __shared__ u32   zrow[64 * 129];
    __shared__ float w2s[10 * 256];
    __shared__ float b2s[10];
    __shared__ float lg[64 * 10];
    int t  = threadIdx.x;
    int r0 = blockIdx.x * 64;
    const u32* zg = (const u32*)z2;
    for (int c = t; c < 64 * 128; c += 256) {
        int row = c >> 7, kc = c & 127;
        zrow[row * 129 + kc] = zg[(u64)(r0 + row) * 128 + kc];
    }
    for (int c = t; c < 2560; c += 256) w2s[c] = W2[c];
    if (t < 10) b2s[t] = b2[t];
    __syncthreads();

    int row = t & 63, og = t >> 6;         // outputs o = og + 4j
    int no = (og < 2) ? 3 : 2;
    float acc[3];
#pragma unroll
    for (int j = 0; j < 3; ++j) acc[j] = (og + 4 * j < 10) ? b2s[og + 4 * j] : 0.0f;
    for (int k2 = 0; k2 < 128; ++k2) {
        u32 pz = zrow[row * 129 + k2];
        float z0 = bf2f((u16)(pz & 0xFFFFu));
        float z1 = bf2f((u16)(pz >> 16));
        for (int j = 0; j < no; ++j) {
            int o = og + 4 * j;
            acc[j] = fmaf(z0, w2s[o * 256 + k2 * 2], acc[j]);
            acc[j] = fmaf(z1, w2s[o * 256 + k2 * 2 + 1], acc[j]);
        }
    }
    for (int j = 0; j < no; ++j) lg[row * 10 + og + 4 * j] = acc[j];
    __syncthreads();

    if (t < 64) {
        float l[10], mx = -1e30f;
#pragma unroll
        for (int o = 0; o < 10; ++o) { l[o] = lg[t * 10 + o]; mx = fmaxf(mx, l[o]); }
        float s = 0.0f;
#pragma unroll
        for (int o = 0; o < 10; ++o) s += expf(l[o] - mx);
        float ls = logf(s);
        float* orow = out + (u64)(r0 + t) * 10;
#pragma unroll
        for (int o = 0; o < 10; ++o) orow[o] = l[o] - mx - ls;
    }
}

// ---------------------------------------------------------------------------
extern "C" void kernel_launch(void* const* d_in, const int* in_sizes, int n_in,
                              void* d_out, int out_size, void* d_ws, size_t ws_size,
                              hipStream_t stream) {
    const float* x    = (const float*)d_in[0];
    const float* L    = (const float*)d_in[1];
    const float* lmax = (const float*)d_in[2];
    const float* cl1W = (const float*)d_in[3];
    const float* cl1b = (const float*)d_in[4];
    const float* fc1W = (const float*)d_in[5];
    const float* fc1b = (const float*)d_in[6];
    const float* gam  = (const float*)d_in[7];
    const float* bet  = (const float*)d_in[8];
    const float* mea  = (const float*)d_in[9];
    const float* var  = (const float*)d_in[10];
    const float* l1W  = (const float*)d_in[11];
    const float* l1b  = (const float*)d_in[12];
    const float* l2W  = (const float*)d_in[13];
    const float* l2b  = (const float*)d_in[14];

    char* ws = (char*)d_ws;
    u32*   packed  = (u32*)(ws + 0);          // 128000 -> 131072
    int*   cnts    = (int*)(ws + 131072);     // 4096
    float* diagw   = (float*)(ws + 135168);   // 4096
    float* bn_a    = (float*)(ws + 139264);   // 4096
    float* bn_c    = (float*)(ws + 143360);   // 4096
    u16*   fc1w_b  = (u16*)(ws + 147456);     // 327680
    u16*   lin1w_b = (u16*)(ws + 475136);     // 131072
    u16*   pooled  = (u16*)(ws + 606208);     // 10485760
    u16*   zbuf    = (u16*)(ws + 11091968);   // 4194304
    u16*   z2buf   = (u16*)(ws + 15286272);   // 4194304  (total ~18.6 MB)
    float* outp    = (float*)d_out;

    k_build<<<dim3(250), dim3(256), 0, stream>>>(L, lmax, packed, cnts, diagw);
    k_pre<<<dim3(640), dim3(256), 0, stream>>>(fc1W, l1W, gam, bet, mea, var,
                                               fc1w_b, lin1w_b, bn_a, bn_c);
    k_cheby<<<dim3(4096), dim3(512), 0, stream>>>(x, (const int4*)packed, cnts, diagw,
                                                  cl1W, cl1b, pooled);
    k_gemm<0><<<dim3(64, 4), dim3(256), 0, stream>>>(pooled, fc1w_b, 640, fc1b,
                                                     bn_a, bn_c, zbuf);
    k_gemm<1><<<dim3(64, 4), dim3(256), 0, stream>>>(zbuf, lin1w_b, 256, l1b,
                                                     bn_a, bn_c, z2buf);
    k_lin2<<<dim3(128), dim3(256), 0, stream>>>(z2buf, l2W, l2b, outp);
}

// Round 4
// 346.484 us; speedup vs baseline: 3.1979x; 3.1979x over previous
//
#include <hip/hip_runtime.h>

typedef unsigned int u32;
typedef unsigned short u16;
typedef unsigned long long u64;

typedef __attribute__((ext_vector_type(8))) short s8v;   // 8 bf16 (4 VGPRs)
typedef __attribute__((ext_vector_type(4))) float f4v;   // 4 fp32 acc

#define B_SZ   8192
#define V_SZ   1000
#define KCH    5
#define MAXDEG 32

__device__ __forceinline__ u16 f2bf(float f) {
    u32 u = __float_as_uint(f);
    u32 r = (u + 0x7FFFu + ((u >> 16) & 1u)) >> 16;   // RNE
    return (u16)r;
}
__device__ __forceinline__ float bf2f(u16 h) { return __uint_as_float(((u32)h) << 16); }

// ---------------------------------------------------------------------------
// K0: build packed sparse Lr (off-diag) + diagonal. One wave per row.
// TRANSPOSED layout: packed4[q4*V + v] is an int4 holding entries 4q4..4q4+3
// of row v -> k_cheby's per-lane loads (consecutive v) are fully coalesced.
// entry: (fp32 weight, low 10 mantissa bits cleared) | col (10 bits); tail = 0.
// ---------------------------------------------------------------------------
__global__ __launch_bounds__(256) void k_build(const float* __restrict__ L,
                                               const float* __restrict__ lmax,
                                               u32* __restrict__ packed,   // [8][V][4] u32
                                               int* __restrict__ cnts,
                                               float* __restrict__ diagw) {
    int wid  = threadIdx.x >> 6;
    int lane = threadIdx.x & 63;
    int row  = blockIdx.x * 4 + wid;
    if (row >= V_SZ) return;
    float s = 2.0f / lmax[0];
    const float* Lrow = L + (u64)row * V_SZ;
    int cnt = 0;
    for (int c0 = 0; c0 < V_SZ; c0 += 64) {
        int c = c0 + lane;
        float val = 0.0f;
        if (c < V_SZ && c != row) val = Lrow[c];
        bool nz = (val != 0.0f);
        u64 m = __ballot(nz);
        int pos = cnt + __popcll(m & ((1ull << lane) - 1ull));
        if (nz && pos < MAXDEG) {
            u32 w = __float_as_uint(val * s);
            packed[((pos >> 2) * V_SZ + row) * 4 + (pos & 3)] = (w & 0xFFFFFC00u) | (u32)c;
        }
        cnt += __popcll(m);
    }
    int cc = cnt < MAXDEG ? cnt : MAXDEG;
    for (int e = cc + lane; e < MAXDEG; e += 64)
        packed[((e >> 2) * V_SZ + row) * 4 + (e & 3)] = 0;
    if (lane == 0) {
        cnts[row]  = cc;
        diagw[row] = s * Lrow[row] - 1.0f;
    }
}

// ---------------------------------------------------------------------------
// Kpre: weight conversions to bf16 (+K padding) and folded BN affine params.
// ---------------------------------------------------------------------------
__global__ __launch_bounds__(256) void k_pre(const float* __restrict__ fc1W,
                                             const float* __restrict__ lin1W,
                                             const float* __restrict__ gam,
                                             const float* __restrict__ bet,
                                             const float* __restrict__ mea,
                                             const float* __restrict__ var,
                                             u16* __restrict__ fc1w_b,
                                             u16* __restrict__ lin1w_b,
                                             float* __restrict__ bn_a,
                                             float* __restrict__ bn_c) {
    int t = blockIdx.x * 256 + threadIdx.x;
    if (t < 256 * 640) {
        int r = t / 640, c = t - r * 640;
        fc1w_b[t] = (c < 625) ? f2bf(fc1W[r * 625 + c]) : (u16)0;
    }
    if (t < 256 * 256) lin1w_b[t] = f2bf(lin1W[t]);
    if (t < 4 * 256) {
        float a = gam[t] * rsqrtf(var[t] + 1e-5f);
        bn_a[t] = a;
        bn_c[t] = bet[t] - mea[t] * a;
    }
}

// ---------------------------------------------------------------------------
// K1: fused Chebyshev recursion + cl1 + ReLU + maxpool8 -> bf16
// 512 threads, 2 rows/thread, 2 batch cols/block.
// Ping-pong 2 LDS stage buffers (16 KB). Coalesced (transposed) sparse loads.
// __launch_bounds__(512,4): 128-VGPR cap -- (512,8) forced a 64-VGPR cap and
// spilled ~3.5 GB/dispatch of scratch to HBM (round-3 943 us regression).
// ---------------------------------------------------------------------------
__global__ __launch_bounds__(512, 4) void k_cheby(const float* __restrict__ x,
                                                  const int4* __restrict__ packed4,
                                                  const int* __restrict__ cnts,
                                                  const float* __restrict__ diagw,
                                                  const float* __restrict__ cl1W,
                                                  const float* __restrict__ cl1b,
                                                  u16* __restrict__ pooled) {
    __shared__ float buf[2][V_SZ * 2];   // [pingpong][v*2 + b] = 16 KB
    __shared__ float cws[25];
    __shared__ float cbs[5];
    int t  = threadIdx.x;
    int b0 = blockIdx.x * 2;

    if (t < 25) cws[t] = cl1W[t];
    if (t < 5)  cbs[t] = cl1b[t];

    const int  v1   = t + 512;
    const bool val1 = (v1 < V_SZ);

    float d0 = diagw[t];
    int   n0 = (cnts[t] + 3) >> 2;
    float d1 = 0.f;
    int   n1 = 0;
    if (val1) { d1 = diagw[v1]; n1 = (cnts[v1] + 3) >> 2; }

    // stage 0 staging: buf[0][v] = (x[b0][v], x[b0+1][v])
    float2 x00, x01;
    x00.x = x[(u64)b0 * V_SZ + t];
    x00.y = x[(u64)(b0 + 1) * V_SZ + t];
    ((float2*)buf[0])[t] = x00;
    x01 = make_float2(0.f, 0.f);
    if (val1) {
        x01.x = x[(u64)b0 * V_SZ + v1];
        x01.y = x[(u64)(b0 + 1) * V_SZ + v1];
        ((float2*)buf[0])[v1] = x01;
    }
    int4 pf0 = packed4[t];                                   // quad 0, row t
    int4 pf1 = val1 ? packed4[v1] : make_int4(0, 0, 0, 0);   // quad 0, row v1
    __syncthreads();

    // feat init with k=0 term
    float2 feat0[5], feat1[5];
#pragma unroll
    for (int f = 0; f < 5; ++f) {
        float w = cws[f * 5];
        feat0[f] = make_float2(w * x00.x, w * x00.y);
        feat1[f] = make_float2(w * x01.x, w * x01.y);
    }

    // stages 1..4
    for (int k = 1; k < KCH; ++k) {
        const float2* prev = (const float2*)buf[(k - 1) & 1];
        float2*       curb = (float2*)buf[k & 1];

        // ---- row 0 (v = t) ----
        {
            float2 pv = prev[t];
            float a0 = d0 * pv.x, a1 = d0 * pv.y;
            int4 pw = pf0;
            int  q  = 0;
            while (true) {
                float2 g0 = prev[(u32)pw.x & 1023u];
                float2 g1 = prev[(u32)pw.y & 1023u];
                float2 g2 = prev[(u32)pw.z & 1023u];
                float2 g3 = prev[(u32)pw.w & 1023u];
                float w0 = __uint_as_float((u32)pw.x & 0xFFFFFC00u);
                float w1 = __uint_as_float((u32)pw.y & 0xFFFFFC00u);
                float w2 = __uint_as_float((u32)pw.z & 0xFFFFFC00u);
                float w3 = __uint_as_float((u32)pw.w & 0xFFFFFC00u);
                a0 = fmaf(w0, g0.x, a0); a1 = fmaf(w0, g0.y, a1);
                a0 = fmaf(w1, g1.x, a0); a1 = fmaf(w1, g1.y, a1);
                a0 = fmaf(w2, g2.x, a0); a1 = fmaf(w2, g2.y, a1);
                a0 = fmaf(w3, g3.x, a0); a1 = fmaf(w3, g3.y, a1);
                if (++q >= n0) break;
                pw = packed4[q * V_SZ + t];                  // coalesced
            }
            if (k >= 2) {
                float2 m2 = curb[t];
                a0 = 2.0f * a0 - m2.x;
                a1 = 2.0f * a1 - m2.y;
            }
            curb[t] = make_float2(a0, a1);
#pragma unroll
            for (int f = 0; f < 5; ++f) {
                float w = cws[f * 5 + k];
                feat0[f].x = fmaf(w, a0, feat0[f].x);
                feat0[f].y = fmaf(w, a1, feat0[f].y);
            }
        }
        // ---- row 1 (v = t + 512) ----
        if (val1) {
            float2 pv = prev[v1];
            float a0 = d1 * pv.x, a1 = d1 * pv.y;
            int4 pw = pf1;
            int  q  = 0;
            while (true) {
                float2 g0 = prev[(u32)pw.x & 1023u];
                float2 g1 = prev[(u32)pw.y & 1023u];
                float2 g2 = prev[(u32)pw.z & 1023u];
                float2 g3 = prev[(u32)pw.w & 1023u];
                float w0 = __uint_as_float((u32)pw.x & 0xFFFFFC00u);
                float w1 = __uint_as_float((u32)pw.y & 0xFFFFFC00u);
                float w2 = __uint_as_float((u32)pw.z & 0xFFFFFC00u);
                float w3 = __uint_as_float((u32)pw.w & 0xFFFFFC00u);
                a0 = fmaf(w0, g0.x, a0); a1 = fmaf(w0, g0.y, a1);
                a0 = fmaf(w1, g1.x, a0); a1 = fmaf(w1, g1.y, a1);
                a0 = fmaf(w2, g2.x, a0); a1 = fmaf(w2, g2.y, a1);
                a0 = fmaf(w3, g3.x, a0); a1 = fmaf(w3, g3.y, a1);
                if (++q >= n1) break;
                pw = packed4[q * V_SZ + v1];
            }
            if (k >= 2) {
                float2 m2 = curb[v1];
                a0 = 2.0f * a0 - m2.x;
                a1 = 2.0f * a1 - m2.y;
            }
            curb[v1] = make_float2(a0, a1);
#pragma unroll
            for (int f = 0; f < 5; ++f) {
                float w = cws[f * 5 + k];
                feat1[f].x = fmaf(w, a0, feat1[f].x);
                feat1[f].y = fmaf(w, a1, feat1[f].y);
            }
        }
        __syncthreads();
    }

    // bias + ReLU + maxpool8 via 8-lane shuffle (8 consecutive v per group)
#pragma unroll
    for (int f = 0; f < 5; ++f) {
#pragma unroll
        for (int b = 0; b < 2; ++b) {
            float s0 = fmaxf((b ? feat0[f].y : feat0[f].x) + cbs[f], 0.0f);
            s0 = fmaxf(s0, __shfl_xor(s0, 1));
            s0 = fmaxf(s0, __shfl_xor(s0, 2));
            s0 = fmaxf(s0, __shfl_xor(s0, 4));
            if ((t & 7) == 0)
                pooled[(u64)(b0 + b) * 640 + (t >> 3) * 5 + f] = f2bf(s0);

            float s1 = val1 ? fmaxf((b ? feat1[f].y : feat1[f].x) + cbs[f], 0.0f) : 0.0f;
            s1 = fmaxf(s1, __shfl_xor(s1, 1));
            s1 = fmaxf(s1, __shfl_xor(s1, 2));
            s1 = fmaxf(s1, __shfl_xor(s1, 4));
            if ((t & 7) == 0 && val1)
                pooled[(u64)(b0 + b) * 640 + (v1 >> 3) * 5 + f] = f2bf(s1);
        }
    }
    // zero the K-padding columns 625..639
    if (t < 30) {
        int b = t / 15, c = 625 + (t % 15);
        pooled[(u64)(b0 + b) * 640 + c] = 0;
    }
}

// ---------------------------------------------------------------------------
// K2/K3: bf16 MFMA GEMM, C[m][n] = sum_k A[m][k]*Bw[n][k] (+epilogue)
// BM=128 BN=64 BK=64, 256 thr (4 waves), wave = 32x64 out = 2x4 MFMA tiles.
// MODE 0: + fc1 bias, BN x4 folded affine + relu, JK max  -> bf16
// MODE 1: + lin1 bias, relu                                -> bf16
// ---------------------------------------------------------------------------
template <int MODE>
__global__ __launch_bounds__(256) void k_gemm(const u16* __restrict__ A,
                                              const u16* __restrict__ Bw,
                                              int Kdim,
                                              const float* __restrict__ bias,
                                              const float* __restrict__ bn_a,
                                              const float* __restrict__ bn_c,
                                              u16* __restrict__ Cout) {
    __shared__ u16 As[128][72];   // +8 pad: row stride 36 dw -> 2-way (free)
    __shared__ u16 Bs[64][72];
    int t    = threadIdx.x;
    int lane = t & 63;
    int wid  = t >> 6;
    int m0   = blockIdx.x * 128;
    int n0   = blockIdx.y * 64;

    f4v acc[2][4];
#pragma unroll
    for (int i = 0; i < 2; ++i)
#pragma unroll
        for (int j = 0; j < 4; ++j) acc[i][j] = (f4v){0.f, 0.f, 0.f, 0.f};

    for (int k0 = 0; k0 < Kdim; k0 += 64) {
        int4 ra[4], rb[2];
#pragma unroll
        for (int i = 0; i < 4; ++i) {
            int c = t + i * 256, row = c >> 3, kc = c & 7;
            ra[i] = *(const int4*)(A + (u64)(m0 + row) * Kdim + k0 + kc * 8);
        }
#pragma unroll
        for (int i = 0; i < 2; ++i) {
            int c = t + i * 256, row = c >> 3, kc = c & 7;
            rb[i] = *(const int4*)(Bw + (u64)(n0 + row) * Kdim + k0 + kc * 8);
        }
        __syncthreads();   // prior iter's LDS reads done
#pragma unroll
        for (int i = 0; i < 4; ++i) {
            int c = t + i * 256, row = c >> 3, kc = c & 7;
            *(int4*)(&As[row][kc * 8]) = ra[i];
        }
#pragma unroll
        for (int i = 0; i < 2; ++i) {
            int c = t + i * 256, row = c >> 3, kc = c & 7;
            *(int4*)(&Bs[row][kc * 8]) = rb[i];
        }
        __syncthreads();
#pragma unroll
        for (int ks = 0; ks < 2; ++ks) {
            int kq = ks * 32 + (lane >> 4) * 8;
            s8v af[2], bf[4];
#pragma unroll
            for (int mt = 0; mt < 2; ++mt) {
                int rl = wid * 32 + mt * 16 + (lane & 15);
                af[mt] = *(const s8v*)(&As[rl][kq]);
            }
#pragma unroll
            for (int nt = 0; nt < 4; ++nt) {
                int cl = nt * 16 + (lane & 15);
                bf[nt] = *(const s8v*)(&Bs[cl][kq]);
            }
#pragma unroll
            for (int mt = 0; mt < 2; ++mt)
#pragma unroll
                for (int nt = 0; nt < 4; ++nt)
                    acc[mt][nt] = __builtin_amdgcn_mfma_f32_16x16x32_bf16(
                        af[mt], bf[nt], acc[mt][nt], 0, 0, 0);
        }
    }

    // epilogue: C/D layout col=lane&15, row=(lane>>4)*4+reg  [m89-verified]
#pragma unroll
    for (int nt = 0; nt < 4; ++nt) {
        int col = n0 + nt * 16 + (lane & 15);
        float bv = bias[col];
        float a_[4], c_[4];
        if (MODE == 0) {
#pragma unroll
            for (int i = 0; i < 4; ++i) {
                a_[i] = bn_a[i * 256 + col];
                c_[i] = bn_c[i * 256 + col];
            }
        }
#pragma unroll
        for (int mt = 0; mt < 2; ++mt) {
            int rbase = m0 + wid * 32 + mt * 16 + (lane >> 4) * 4;
#pragma unroll
            for (int r = 0; r < 4; ++r) {
                float v = acc[mt][nt][r] + bv;
                if (MODE == 0) {
                    float h = v, z = 0.0f;
#pragma unroll
                    for (int i = 0; i < 4; ++i) {
                        h = fmaxf(fmaf(a_[i], h, c_[i]), 0.0f);
                        z = fmaxf(z, h);
                    }
                    v = z;
                } else {
                    v = fmaxf(v, 0.0f);
                }
                Cout[(u64)(rbase + r) * 256 + col] = f2bf(v);
            }
        }
    }
}

// ---------------------------------------------------------------------------
// K4: lin2 ([8192,256]@[10,256]^T + b) + log_softmax -> fp32 out
// 64 rows per block, rows staged in LDS (stride 129 dw: conflict-free).
// ---------------------------------------------------------------------------
__global__ __launch_bounds__(256) void k_lin2(const u16* __restrict__ z2,
                                              const float* __restrict__ W2,
                                              const float* __restrict__ b2,
                                              float* __restrict__ out) {
    __shared__ u32   zrow[64 * 129];
    __shared__ float w2s[10 * 256];
    __shared__ float b2s[10];
    __shared__ float lg[64 * 10];
    int t  = threadIdx.x;
    int r0 = blockIdx.x * 64;
    const u32* zg = (const u32*)z2;
    for (int c = t; c < 64 * 128; c += 256) {
        int row = c >> 7, kc = c & 127;
        zrow[row * 129 + kc] = zg[(u64)(r0 + row) * 128 + kc];
    }
    for (int c = t; c < 2560; c += 256) w2s[c] = W2[c];
    if (t < 10) b2s[t] = b2[t];
    __syncthreads();

    int row = t & 63, og = t >> 6;         // outputs o = og + 4j
    int no = (og < 2) ? 3 : 2;
    float acc[3];
#pragma unroll
    for (int j = 0; j < 3; ++j) acc[j] = (og + 4 * j < 10) ? b2s[og + 4 * j] : 0.0f;
    for (int k2 = 0; k2 < 128; ++k2) {
        u32 pz = zrow[row * 129 + k2];
        float z0 = bf2f((u16)(pz & 0xFFFFu));
        float z1 = bf2f((u16)(pz >> 16));
        for (int j = 0; j < no; ++j) {
            int o = og + 4 * j;
            acc[j] = fmaf(z0, w2s[o * 256 + k2 * 2], acc[j]);
            acc[j] = fmaf(z1, w2s[o * 256 + k2 * 2 + 1], acc[j]);
        }
    }
    for (int j = 0; j < no; ++j) lg[row * 10 + og + 4 * j] = acc[j];
    __syncthreads();

    if (t < 64) {
        float l[10], mx = -1e30f;
#pragma unroll
        for (int o = 0; o < 10; ++o) { l[o] = lg[t * 10 + o]; mx = fmaxf(mx, l[o]); }
        float s = 0.0f;
#pragma unroll
        for (int o = 0; o < 10; ++o) s += expf(l[o] - mx);
        float ls = logf(s);
        float* orow = out + (u64)(r0 + t) * 10;
#pragma unroll
        for (int o = 0; o < 10; ++o) orow[o] = l[o] - mx - ls;
    }
}

// ---------------------------------------------------------------------------
extern "C" void kernel_launch(void* const* d_in, const int* in_sizes, int n_in,
                              void* d_out, int out_size, void* d_ws, size_t ws_size,
                              hipStream_t stream) {
    const float* x    = (const float*)d_in[0];
    const float* L    = (const float*)d_in[1];
    const float* lmax = (const float*)d_in[2];
    const float* cl1W = (const float*)d_in[3];
    const float* cl1b = (const float*)d_in[4];
    const float* fc1W = (const float*)d_in[5];
    const float* fc1b = (const float*)d_in[6];
    const float* gam  = (const float*)d_in[7];
    const float* bet  = (const float*)d_in[8];
    const float* mea  = (const float*)d_in[9];
    const float* var  = (const float*)d_in[10];
    const float* l1W  = (const float*)d_in[11];
    const float* l1b  = (const float*)d_in[12];
    const float* l2W  = (const float*)d_in[13];
    const float* l2b  = (const float*)d_in[14];

    char* ws = (char*)d_ws;
    u32*   packed  = (u32*)(ws + 0);          // 128000 -> 131072
    int*   cnts    = (int*)(ws + 131072);     // 4096
    float* diagw   = (float*)(ws + 135168);   // 4096
    float* bn_a    = (float*)(ws + 139264);   // 4096
    float* bn_c    = (float*)(ws + 143360);   // 4096
    u16*   fc1w_b  = (u16*)(ws + 147456);     // 327680
    u16*   lin1w_b = (u16*)(ws + 475136);     // 131072
    u16*   pooled  = (u16*)(ws + 606208);     // 10485760
    u16*   zbuf    = (u16*)(ws + 11091968);   // 4194304
    u16*   z2buf   = (u16*)(ws + 15286272);   // 4194304  (total ~18.6 MB)
    float* outp    = (float*)d_out;

    k_build<<<dim3(250), dim3(256), 0, stream>>>(L, lmax, packed, cnts, diagw);
    k_pre<<<dim3(640), dim3(256), 0, stream>>>(fc1W, l1W, gam, bet, mea, var,
                                               fc1w_b, lin1w_b, bn_a, bn_c);
    k_cheby<<<dim3(4096), dim3(512), 0, stream>>>(x, (const int4*)packed, cnts, diagw,
                                                  cl1W, cl1b, pooled);
    k_gemm<0><<<dim3(64, 4), dim3(256), 0, stream>>>(pooled, fc1w_b, 640, fc1b,
                                                     bn_a, bn_c, zbuf);
    k_gemm<1><<<dim3(64, 4), dim3(256), 0, stream>>>(zbuf, lin1w_b, 256, l1b,
                                                     bn_a, bn_c, z2buf);
    k_lin2<<<dim3(128), dim3(256), 0, stream>>>(z2buf, l2W, l2b, outp);
}

// Round 5
// 272.308 us; speedup vs baseline: 4.0691x; 1.2724x over previous
//
#include <hip/hip_runtime.h>

typedef unsigned int u32;
typedef unsigned short u16;
typedef unsigned long long u64;

typedef __attribute__((ext_vector_type(8))) short s8v;   // 8 bf16 (4 VGPRs)
typedef __attribute__((ext_vector_type(4))) float f4v;   // 4 fp32 acc

#define B_SZ   8192
#define V_SZ   1000
#define KCH    5
#define MAXDEG 32

__device__ __forceinline__ u16 f2bf(float f) {
    u32 u = __float_as_uint(f);
    u32 r = (u + 0x7FFFu + ((u >> 16) & 1u)) >> 16;   // RNE
    return (u16)r;
}
__device__ __forceinline__ float bf2f(u16 h) { return __uint_as_float(((u32)h) << 16); }

// ---------------------------------------------------------------------------
// K0: build packed sparse Lr (off-diag) + diagonal. One wave per row.
// TRANSPOSED layout: packed4[q4*V + v] is an int4 holding entries 4q4..4q4+3
// of row v -> k_cheby's per-lane loads (consecutive v) are fully coalesced.
// entry: (fp32 weight, low 10 mantissa bits cleared) | col (10 bits); tail = 0.
// ---------------------------------------------------------------------------
__global__ __launch_bounds__(256) void k_build(const float* __restrict__ L,
                                               const float* __restrict__ lmax,
                                               u32* __restrict__ packed,   // [8][V][4] u32
                                               int* __restrict__ cnts,
                                               float* __restrict__ diagw) {
    int wid  = threadIdx.x >> 6;
    int lane = threadIdx.x & 63;
    int row  = blockIdx.x * 4 + wid;
    if (row >= V_SZ) return;
    float s = 2.0f / lmax[0];
    const float* Lrow = L + (u64)row * V_SZ;
    int cnt = 0;
    for (int c0 = 0; c0 < V_SZ; c0 += 64) {
        int c = c0 + lane;
        float val = 0.0f;
        if (c < V_SZ && c != row) val = Lrow[c];
        bool nz = (val != 0.0f);
        u64 m = __ballot(nz);
        int pos = cnt + __popcll(m & ((1ull << lane) - 1ull));
        if (nz && pos < MAXDEG) {
            u32 w = __float_as_uint(val * s);
            packed[((pos >> 2) * V_SZ + row) * 4 + (pos & 3)] = (w & 0xFFFFFC00u) | (u32)c;
        }
        cnt += __popcll(m);
    }
    int cc = cnt < MAXDEG ? cnt : MAXDEG;
    for (int e = cc + lane; e < MAXDEG; e += 64)
        packed[((e >> 2) * V_SZ + row) * 4 + (e & 3)] = 0;
    if (lane == 0) {
        cnts[row]  = cc;
        diagw[row] = s * Lrow[row] - 1.0f;
    }
}

// ---------------------------------------------------------------------------
// Kpre: weight conversions to bf16 (+K padding) and folded BN affine params.
// ---------------------------------------------------------------------------
__global__ __launch_bounds__(256) void k_pre(const float* __restrict__ fc1W,
                                             const float* __restrict__ lin1W,
                                             const float* __restrict__ gam,
                                             const float* __restrict__ bet,
                                             const float* __restrict__ mea,
                                             const float* __restrict__ var,
                                             u16* __restrict__ fc1w_b,
                                             u16* __restrict__ lin1w_b,
                                             float* __restrict__ bn_a,
                                             float* __restrict__ bn_c) {
    int t = blockIdx.x * 256 + threadIdx.x;
    if (t < 256 * 640) {
        int r = t / 640, c = t - r * 640;
        fc1w_b[t] = (c < 625) ? f2bf(fc1W[r * 625 + c]) : (u16)0;
    }
    if (t < 256 * 256) lin1w_b[t] = f2bf(lin1W[t]);
    if (t < 4 * 256) {
        float a = gam[t] * rsqrtf(var[t] + 1e-5f);
        bn_a[t] = a;
        bn_c[t] = bet[t] - mea[t] * a;
    }
}

// ---------------------------------------------------------------------------
// K1: fused Chebyshev recursion + cl1 + ReLU + maxpool8 -> bf16
// 512 threads, 2 rows/thread, 4 batch cols/block (amortizes sparse decode).
// Ping-pong 2 LDS float4 stage buffers (32 KB). Coalesced sparse loads with
// prefetch-1. x_{k-1}, x_{k-2} of own rows kept in registers (no LDS re-read).
// (512,4): 128-VGPR cap -- (512,8)'s 64-cap spilled 3.5 GB/dispatch (round 3).
// ---------------------------------------------------------------------------
__global__ __launch_bounds__(512, 4) void k_cheby(const float* __restrict__ x,
                                                  const int4* __restrict__ packed4,
                                                  const int* __restrict__ cnts,
                                                  const float* __restrict__ diagw,
                                                  const float* __restrict__ cl1W,
                                                  const float* __restrict__ cl1b,
                                                  u16* __restrict__ pooled) {
    __shared__ float4 buf[2][V_SZ];   // [pingpong][v] = 4 batch cols, 32 KB
    __shared__ float cws[25];
    __shared__ float cbs[5];
    int t  = threadIdx.x;
    int b0 = blockIdx.x * 4;

    if (t < 25) cws[t] = cl1W[t];
    if (t < 5)  cbs[t] = cl1b[t];

    const int  v1   = t + 512;
    const bool val1 = (v1 < V_SZ);

    float d0 = diagw[t];
    int   n0 = (cnts[t] + 3) >> 2;
    float d1 = 0.f;
    int   n1 = 0;
    if (val1) { d1 = diagw[v1]; n1 = (cnts[v1] + 3) >> 2; }

    // stage-0 staging: buf[0][v] = x[b0..b0+3][v]; own values kept in regs
    float4 pm1_0, pm2_0, pm1_1, pm2_1;
    {
        float4 a;
        a.x = x[(u64)(b0 + 0) * V_SZ + t];
        a.y = x[(u64)(b0 + 1) * V_SZ + t];
        a.z = x[(u64)(b0 + 2) * V_SZ + t];
        a.w = x[(u64)(b0 + 3) * V_SZ + t];
        buf[0][t] = a;
        pm1_0 = a; pm2_0 = a;
        float4 b = make_float4(0.f, 0.f, 0.f, 0.f);
        if (val1) {
            b.x = x[(u64)(b0 + 0) * V_SZ + v1];
            b.y = x[(u64)(b0 + 1) * V_SZ + v1];
            b.z = x[(u64)(b0 + 2) * V_SZ + v1];
            b.w = x[(u64)(b0 + 3) * V_SZ + v1];
            buf[0][v1] = b;
        }
        pm1_1 = b; pm2_1 = b;
    }
    __syncthreads();

    // feat init with k=0 term
    float4 feat0[5], feat1[5];
#pragma unroll
    for (int f = 0; f < 5; ++f) {
        float w = cws[f * 5];
        feat0[f] = make_float4(w * pm1_0.x, w * pm1_0.y, w * pm1_0.z, w * pm1_0.w);
        feat1[f] = make_float4(w * pm1_1.x, w * pm1_1.y, w * pm1_1.z, w * pm1_1.w);
    }

    // stages 1..4 (fully unrolled)
#pragma unroll
    for (int k = 1; k < KCH; ++k) {
        const float4* prevb = buf[(k - 1) & 1];
        float4*       curb  = buf[k & 1];

        // ---- row 0 (v = t) ----
        {
            float4 a = make_float4(d0 * pm1_0.x, d0 * pm1_0.y,
                                   d0 * pm1_0.z, d0 * pm1_0.w);
            int4 pw = packed4[t];
            for (int q = 0; q < n0; ++q) {
                int4 pwn = pw;
                if (q + 1 < n0) pwn = packed4[(q + 1) * V_SZ + t];
                float4 g0 = prevb[(u32)pw.x & 1023u];
                float4 g1 = prevb[(u32)pw.y & 1023u];
                float4 g2 = prevb[(u32)pw.z & 1023u];
                float4 g3 = prevb[(u32)pw.w & 1023u];
                float w0 = __uint_as_float((u32)pw.x & 0xFFFFFC00u);
                float w1 = __uint_as_float((u32)pw.y & 0xFFFFFC00u);
                float w2 = __uint_as_float((u32)pw.z & 0xFFFFFC00u);
                float w3 = __uint_as_float((u32)pw.w & 0xFFFFFC00u);
                a.x = fmaf(w0, g0.x, a.x); a.y = fmaf(w0, g0.y, a.y);
                a.z = fmaf(w0, g0.z, a.z); a.w = fmaf(w0, g0.w, a.w);
                a.x = fmaf(w1, g1.x, a.x); a.y = fmaf(w1, g1.y, a.y);
                a.z = fmaf(w1, g1.z, a.z); a.w = fmaf(w1, g1.w, a.w);
                a.x = fmaf(w2, g2.x, a.x); a.y = fmaf(w2, g2.y, a.y);
                a.z = fmaf(w2, g2.z, a.z); a.w = fmaf(w2, g2.w, a.w);
                a.x = fmaf(w3, g3.x, a.x); a.y = fmaf(w3, g3.y, a.y);
                a.z = fmaf(w3, g3.z, a.z); a.w = fmaf(w3, g3.w, a.w);
                pw = pwn;
            }
            if (k >= 2) {
                a.x = fmaf(2.0f, a.x, -pm2_0.x);
                a.y = fmaf(2.0f, a.y, -pm2_0.y);
                a.z = fmaf(2.0f, a.z, -pm2_0.z);
                a.w = fmaf(2.0f, a.w, -pm2_0.w);
            }
            curb[t] = a;
            pm2_0 = pm1_0; pm1_0 = a;
#pragma unroll
            for (int f = 0; f < 5; ++f) {
                float w = cws[f * 5 + k];
                feat0[f].x = fmaf(w, a.x, feat0[f].x);
                feat0[f].y = fmaf(w, a.y, feat0[f].y);
                feat0[f].z = fmaf(w, a.z, feat0[f].z);
                feat0[f].w = fmaf(w, a.w, feat0[f].w);
            }
        }
        // ---- row 1 (v = t + 512) ----
        if (val1) {
            float4 a = make_float4(d1 * pm1_1.x, d1 * pm1_1.y,
                                   d1 * pm1_1.z, d1 * pm1_1.w);
            int4 pw = packed4[v1];
            for (int q = 0; q < n1; ++q) {
                int4 pwn = pw;
                if (q + 1 < n1) pwn = packed4[(q + 1) * V_SZ + v1];
                float4 g0 = prevb[(u32)pw.x & 1023u];
                float4 g1 = prevb[(u32)pw.y & 1023u];
                float4 g2 = prevb[(u32)pw.z & 1023u];
                float4 g3 = prevb[(u32)pw.w & 1023u];
                float w0 = __uint_as_float((u32)pw.x & 0xFFFFFC00u);
                float w1 = __uint_as_float((u32)pw.y & 0xFFFFFC00u);
                float w2 = __uint_as_float((u32)pw.z & 0xFFFFFC00u);
                float w3 = __uint_as_float((u32)pw.w & 0xFFFFFC00u);
                a.x = fmaf(w0, g0.x, a.x); a.y = fmaf(w0, g0.y, a.y);
                a.z = fmaf(w0, g0.z, a.z); a.w = fmaf(w0, g0.w, a.w);
                a.x = fmaf(w1, g1.x, a.x); a.y = fmaf(w1, g1.y, a.y);
                a.z = fmaf(w1, g1.z, a.z); a.w = fmaf(w1, g1.w, a.w);
                a.x = fmaf(w2, g2.x, a.x); a.y = fmaf(w2, g2.y, a.y);
                a.z = fmaf(w2, g2.z, a.z); a.w = fmaf(w2, g2.w, a.w);
                a.x = fmaf(w3, g3.x, a.x); a.y = fmaf(w3, g3.y, a.y);
                a.z = fmaf(w3, g3.z, a.z); a.w = fmaf(w3, g3.w, a.w);
                pw = pwn;
            }
            if (k >= 2) {
                a.x = fmaf(2.0f, a.x, -pm2_1.x);
                a.y = fmaf(2.0f, a.y, -pm2_1.y);
                a.z = fmaf(2.0f, a.z, -pm2_1.z);
                a.w = fmaf(2.0f, a.w, -pm2_1.w);
            }
            curb[v1] = a;
            pm2_1 = pm1_1; pm1_1 = a;
#pragma unroll
            for (int f = 0; f < 5; ++f) {
                float w = cws[f * 5 + k];
                feat1[f].x = fmaf(w, a.x, feat1[f].x);
                feat1[f].y = fmaf(w, a.y, feat1[f].y);
                feat1[f].z = fmaf(w, a.z, feat1[f].z);
                feat1[f].w = fmaf(w, a.w, feat1[f].w);
            }
        }
        __syncthreads();
    }

    // bias + ReLU + maxpool8 via 8-lane shuffle (8 consecutive v per group)
#pragma unroll
    for (int f = 0; f < 5; ++f) {
#pragma unroll
        for (int b = 0; b < 4; ++b) {
            float c0 = (b == 0) ? feat0[f].x : (b == 1) ? feat0[f].y
                     : (b == 2) ? feat0[f].z : feat0[f].w;
            float s0 = fmaxf(c0 + cbs[f], 0.0f);
            s0 = fmaxf(s0, __shfl_xor(s0, 1));
            s0 = fmaxf(s0, __shfl_xor(s0, 2));
            s0 = fmaxf(s0, __shfl_xor(s0, 4));
            if ((t & 7) == 0)
                pooled[(u64)(b0 + b) * 640 + (t >> 3) * 5 + f] = f2bf(s0);

            float c1 = (b == 0) ? feat1[f].x : (b == 1) ? feat1[f].y
                     : (b == 2) ? feat1[f].z : feat1[f].w;
            float s1 = val1 ? fmaxf(c1 + cbs[f], 0.0f) : 0.0f;
            s1 = fmaxf(s1, __shfl_xor(s1, 1));
            s1 = fmaxf(s1, __shfl_xor(s1, 2));
            s1 = fmaxf(s1, __shfl_xor(s1, 4));
            if ((t & 7) == 0 && val1)
                pooled[(u64)(b0 + b) * 640 + (v1 >> 3) * 5 + f] = f2bf(s1);
        }
    }
    // zero the K-padding columns 625..639 for the 4 batch rows
    if (t < 60) {
        int b = t / 15, c = 625 + (t % 15);
        pooled[(u64)(b0 + b) * 640 + c] = 0;
    }
}

// ---------------------------------------------------------------------------
// K2/K3: bf16 MFMA GEMM, C[m][n] = sum_k A[m][k]*Bw[n][k] (+epilogue)
// BM=128 BN=64 BK=64, 256 thr (4 waves), wave = 32x64 out = 2x4 MFMA tiles.
// MODE 0: + fc1 bias, BN x4 folded affine + relu, JK max  -> bf16
// MODE 1: + lin1 bias, relu                                -> bf16
// ---------------------------------------------------------------------------
template <int MODE>
__global__ __launch_bounds__(256) void k_gemm(const u16* __restrict__ A,
                                              const u16* __restrict__ Bw,
                                              int Kdim,
                                              const float* __restrict__ bias,
                                              const float* __restrict__ bn_a,
                                              const float* __restrict__ bn_c,
                                              u16* __restrict__ Cout) {
    __shared__ u16 As[128][72];   // +8 pad: row stride 36 dw -> 2-way (free)
    __shared__ u16 Bs[64][72];
    int t    = threadIdx.x;
    int lane = t & 63;
    int wid  = t >> 6;
    int m0   = blockIdx.x * 128;
    int n0   = blockIdx.y * 64;

    f4v acc[2][4];
#pragma unroll
    for (int i = 0; i < 2; ++i)
#pragma unroll
        for (int j = 0; j < 4; ++j) acc[i][j] = (f4v){0.f, 0.f, 0.f, 0.f};

    for (int k0 = 0; k0 < Kdim; k0 += 64) {
        int4 ra[4], rb[2];
#pragma unroll
        for (int i = 0; i < 4; ++i) {
            int c = t + i * 256, row = c >> 3, kc = c & 7;
            ra[i] = *(const int4*)(A + (u64)(m0 + row) * Kdim + k0 + kc * 8);
        }
#pragma unroll
        for (int i = 0; i < 2; ++i) {
            int c = t + i * 256, row = c >> 3, kc = c & 7;
            rb[i] = *(const int4*)(Bw + (u64)(n0 + row) * Kdim + k0 + kc * 8);
        }
        __syncthreads();   // prior iter's LDS reads done
#pragma unroll
        for (int i = 0; i < 4; ++i) {
            int c = t + i * 256, row = c >> 3, kc = c & 7;
            *(int4*)(&As[row][kc * 8]) = ra[i];
        }
#pragma unroll
        for (int i = 0; i < 2; ++i) {
            int c = t + i * 256, row = c >> 3, kc = c & 7;
            *(int4*)(&Bs[row][kc * 8]) = rb[i];
        }
        __syncthreads();
#pragma unroll
        for (int ks = 0; ks < 2; ++ks) {
            int kq = ks * 32 + (lane >> 4) * 8;
            s8v af[2], bf[4];
#pragma unroll
            for (int mt = 0; mt < 2; ++mt) {
                int rl = wid * 32 + mt * 16 + (lane & 15);
                af[mt] = *(const s8v*)(&As[rl][kq]);
            }
#pragma unroll
            for (int nt = 0; nt < 4; ++nt) {
                int cl = nt * 16 + (lane & 15);
                bf[nt] = *(const s8v*)(&Bs[cl][kq]);
            }
#pragma unroll
            for (int mt = 0; mt < 2; ++mt)
#pragma unroll
                for (int nt = 0; nt < 4; ++nt)
                    acc[mt][nt] = __builtin_amdgcn_mfma_f32_16x16x32_bf16(
                        af[mt], bf[nt], acc[mt][nt], 0, 0, 0);
        }
    }

    // epilogue: C/D layout col=lane&15, row=(lane>>4)*4+reg  [m89-verified]
#pragma unroll
    for (int nt = 0; nt < 4; ++nt) {
        int col = n0 + nt * 16 + (lane & 15);
        float bv = bias[col];
        float a_[4], c_[4];
        if (MODE == 0) {
#pragma unroll
            for (int i = 0; i < 4; ++i) {
                a_[i] = bn_a[i * 256 + col];
                c_[i] = bn_c[i * 256 + col];
            }
        }
#pragma unroll
        for (int mt = 0; mt < 2; ++mt) {
            int rbase = m0 + wid * 32 + mt * 16 + (lane >> 4) * 4;
#pragma unroll
            for (int r = 0; r < 4; ++r) {
                float v = acc[mt][nt][r] + bv;
                if (MODE == 0) {
                    float h = v, z = 0.0f;
#pragma unroll
                    for (int i = 0; i < 4; ++i) {
                        h = fmaxf(fmaf(a_[i], h, c_[i]), 0.0f);
                        z = fmaxf(z, h);
                    }
                    v = z;
                } else {
                    v = fmaxf(v, 0.0f);
                }
                Cout[(u64)(rbase + r) * 256 + col] = f2bf(v);
            }
        }
    }
}

// ---------------------------------------------------------------------------
// K4: lin2 ([8192,256]@[10,256]^T + b) + log_softmax -> fp32 out
// 64 rows per block, rows staged in LDS (stride 129 dw: conflict-free).
// ---------------------------------------------------------------------------
__global__ __launch_bounds__(256) void k_lin2(const u16* __restrict__ z2,
                                              const float* __restrict__ W2,
                                              const float* __restrict__ b2,
                                              float* __restrict__ out) {
    __shared__ u32   zrow[64 * 129];
    __shared__ float w2s[10 * 256];
    __shared__ float b2s[10];
    __shared__ float lg[64 * 10];
    int t  = threadIdx.x;
    int r0 = blockIdx.x * 64;
    const u32* zg = (const u32*)z2;
    for (int c = t; c < 64 * 128; c += 256) {
        int row = c >> 7, kc = c & 127;
        zrow[row * 129 + kc] = zg[(u64)(r0 + row) * 128 + kc];
    }
    for (int c = t; c < 2560; c += 256) w2s[c] = W2[c];
    if (t < 10) b2s[t] = b2[t];
    __syncthreads();

    int row = t & 63, og = t >> 6;         // outputs o = og + 4j
    int no = (og < 2) ? 3 : 2;
    float acc[3];
#pragma unroll
    for (int j = 0; j < 3; ++j) acc[j] = (og + 4 * j < 10) ? b2s[og + 4 * j] : 0.0f;
    for (int k2 = 0; k2 < 128; ++k2) {
        u32 pz = zrow[row * 129 + k2];
        float z0 = bf2f((u16)(pz & 0xFFFFu));
        float z1 = bf2f((u16)(pz >> 16));
        for (int j = 0; j < no; ++j) {
            int o = og + 4 * j;
            acc[j] = fmaf(z0, w2s[o * 256 + k2 * 2], acc[j]);
            acc[j] = fmaf(z1, w2s[o * 256 + k2 * 2 + 1], acc[j]);
        }
    }
    for (int j = 0; j < no; ++j) lg[row * 10 + og + 4 * j] = acc[j];
    __syncthreads();

    if (t < 64) {
        float l[10], mx = -1e30f;
#pragma unroll
        for (int o = 0; o < 10; ++o) { l[o] = lg[t * 10 + o]; mx = fmaxf(mx, l[o]); }
        float s = 0.0f;
#pragma unroll
        for (int o = 0; o < 10; ++o) s += expf(l[o] - mx);
        float ls = logf(s);
        float* orow = out + (u64)(r0 + t) * 10;
#pragma unroll
        for (int o = 0; o < 10; ++o) orow[o] = l[o] - mx - ls;
    }
}

// ---------------------------------------------------------------------------
extern "C" void kernel_launch(void* const* d_in, const int* in_sizes, int n_in,
                              void* d_out, int out_size, void* d_ws, size_t ws_size,
                              hipStream_t stream) {
    const float* x    = (const float*)d_in[0];
    const float* L    = (const float*)d_in[1];
    const float* lmax = (const float*)d_in[2];
    const float* cl1W = (const float*)d_in[3];
    const float* cl1b = (const float*)d_in[4];
    const float* fc1W = (const float*)d_in[5];
    const float* fc1b = (const float*)d_in[6];
    const float* gam  = (const float*)d_in[7];
    const float* bet  = (const float*)d_in[8];
    const float* mea  = (const float*)d_in[9];
    const float* var  = (const float*)d_in[10];
    const float* l1W  = (const float*)d_in[11];
    const float* l1b  = (const float*)d_in[12];
    const float* l2W  = (const float*)d_in[13];
    const float* l2b  = (const float*)d_in[14];

    char* ws = (char*)d_ws;
    u32*   packed  = (u32*)(ws + 0);          // 128000 -> 131072
    int*   cnts    = (int*)(ws + 131072);     // 4096
    float* diagw   = (float*)(ws + 135168);   // 4096
    float* bn_a    = (float*)(ws + 139264);   // 4096
    float* bn_c    = (float*)(ws + 143360);   // 4096
    u16*   fc1w_b  = (u16*)(ws + 147456);     // 327680
    u16*   lin1w_b = (u16*)(ws + 475136);     // 131072
    u16*   pooled  = (u16*)(ws + 606208);     // 10485760
    u16*   zbuf    = (u16*)(ws + 11091968);   // 4194304
    u16*   z2buf   = (u16*)(ws + 15286272);   // 4194304  (total ~18.6 MB)
    float* outp    = (float*)d_out;

    k_build<<<dim3(250), dim3(256), 0, stream>>>(L, lmax, packed, cnts, diagw);
    k_pre<<<dim3(640), dim3(256), 0, stream>>>(fc1W, l1W, gam, bet, mea, var,
                                               fc1w_b, lin1w_b, bn_a, bn_c);
    k_cheby<<<dim3(2048), dim3(512), 0, stream>>>(x, (const int4*)packed, cnts, diagw,
                                                  cl1W, cl1b, pooled);
    k_gemm<0><<<dim3(64, 4), dim3(256), 0, stream>>>(pooled, fc1w_b, 640, fc1b,
                                                     bn_a, bn_c, zbuf);
    k_gemm<1><<<dim3(64, 4), dim3(256), 0, stream>>>(zbuf, lin1w_b, 256, l1b,
                                                     bn_a, bn_c, z2buf);
    k_lin2<<<dim3(128), dim3(256), 0, stream>>>(z2buf, l2W, l2b, outp);
}

// Round 7
// 238.967 us; speedup vs baseline: 4.6368x; 1.1395x over previous
//
#include <hip/hip_runtime.h>

typedef unsigned int u32;
typedef unsigned short u16;
typedef unsigned long long u64;

typedef __attribute__((ext_vector_type(8))) short s8v;   // 8 bf16 (4 VGPRs)
typedef __attribute__((ext_vector_type(4))) float f4v;   // 4 fp32 acc

#define B_SZ   8192
#define V_SZ   1000
#define KCH    5
#define MAXDEG 32

__device__ __forceinline__ u16 f2bf(float f) {
    u32 u = __float_as_uint(f);
    u32 r = (u + 0x7FFFu + ((u >> 16) & 1u)) >> 16;   // RNE
    return (u16)r;
}
__device__ __forceinline__ float bf2f(u16 h) { return __uint_as_float(((u32)h) << 16); }

// ---------------------------------------------------------------------------
// K0: fused prep = {sparse build of Lr} U {weight bf16 conversion + BN fold}.
// blocks 0..249: build (wave-per-row scan of dense L, transposed packed4 out)
// blocks 250..889: weight conversion work.
// packed4[q4*V + v] int4 = entries 4q4..4q4+3 of row v (coalesced in k_cheby);
// entry = (fp32 weight, low 10 mantissa bits cleared) | col(10b); tail = 0.
// ---------------------------------------------------------------------------
__global__ __launch_bounds__(256) void k_prep(const float* __restrict__ L,
                                              const float* __restrict__ lmax,
                                              u32* __restrict__ packed,
                                              int* __restrict__ cnts,
                                              float* __restrict__ diagw,
                                              const float* __restrict__ fc1W,
                                              const float* __restrict__ lin1W,
                                              const float* __restrict__ gam,
                                              const float* __restrict__ bet,
                                              const float* __restrict__ mea,
                                              const float* __restrict__ var,
                                              u16* __restrict__ fc1w_b,
                                              u16* __restrict__ lin1w_b,
                                              float* __restrict__ bn_a,
                                              float* __restrict__ bn_c) {
    if (blockIdx.x < 250) {
        int wid  = threadIdx.x >> 6;
        int lane = threadIdx.x & 63;
        int row  = blockIdx.x * 4 + wid;
        if (row >= V_SZ) return;
        float s = 2.0f / lmax[0];
        const float* Lrow = L + (u64)row * V_SZ;
        int cnt = 0;
        for (int c0 = 0; c0 < V_SZ; c0 += 64) {
            int c = c0 + lane;
            float val = 0.0f;
            if (c < V_SZ && c != row) val = Lrow[c];
            bool nz = (val != 0.0f);
            u64 m = __ballot(nz);
            int pos = cnt + __popcll(m & ((1ull << lane) - 1ull));
            if (nz && pos < MAXDEG) {
                u32 w = __float_as_uint(val * s);
                packed[((pos >> 2) * V_SZ + row) * 4 + (pos & 3)] = (w & 0xFFFFFC00u) | (u32)c;
            }
            cnt += __popcll(m);
        }
        int cc = cnt < MAXDEG ? cnt : MAXDEG;
        for (int e = cc + lane; e < MAXDEG; e += 64)
            packed[((e >> 2) * V_SZ + row) * 4 + (e & 3)] = 0;
        if (lane == 0) {
            cnts[row]  = cc;
            diagw[row] = s * Lrow[row] - 1.0f;
        }
    } else {
        int t = (blockIdx.x - 250) * 256 + threadIdx.x;
        if (t < 256 * 640) {
            int r = t / 640, c = t - r * 640;
            fc1w_b[t] = (c < 625) ? f2bf(fc1W[r * 625 + c]) : (u16)0;
        }
        if (t < 256 * 256) lin1w_b[t] = f2bf(lin1W[t]);
        if (t < 4 * 256) {
            float a = gam[t] * rsqrtf(var[t] + 1e-5f);
            bn_a[t] = a;
            bn_c[t] = bet[t] - mea[t] * a;
        }
    }
}

// ---------------------------------------------------------------------------
// K1: fused Chebyshev recursion + cl1 + ReLU + maxpool8 -> bf16 (unchanged
// from round 5: 94 us, VALU/LDS balanced, no spills at (512,4)).
// ---------------------------------------------------------------------------
__global__ __launch_bounds__(512, 4) void k_cheby(const float* __restrict__ x,
                                                  const int4* __restrict__ packed4,
                                                  const int* __restrict__ cnts,
                                                  const float* __restrict__ diagw,
                                                  const float* __restrict__ cl1W,
                                                  const float* __restrict__ cl1b,
                                                  u16* __restrict__ pooled) {
    __shared__ float4 buf[2][V_SZ];   // [pingpong][v] = 4 batch cols, 32 KB
    __shared__ float cws[25];
    __shared__ float cbs[5];
    int t  = threadIdx.x;
    int b0 = blockIdx.x * 4;

    if (t < 25) cws[t] = cl1W[t];
    if (t < 5)  cbs[t] = cl1b[t];

    const int  v1   = t + 512;
    const bool val1 = (v1 < V_SZ);

    float d0 = diagw[t];
    int   n0 = (cnts[t] + 3) >> 2;
    float d1 = 0.f;
    int   n1 = 0;
    if (val1) { d1 = diagw[v1]; n1 = (cnts[v1] + 3) >> 2; }

    float4 pm1_0, pm2_0, pm1_1, pm2_1;
    {
        float4 a;
        a.x = x[(u64)(b0 + 0) * V_SZ + t];
        a.y = x[(u64)(b0 + 1) * V_SZ + t];
        a.z = x[(u64)(b0 + 2) * V_SZ + t];
        a.w = x[(u64)(b0 + 3) * V_SZ + t];
        buf[0][t] = a;
        pm1_0 = a; pm2_0 = a;
        float4 b = make_float4(0.f, 0.f, 0.f, 0.f);
        if (val1) {
            b.x = x[(u64)(b0 + 0) * V_SZ + v1];
            b.y = x[(u64)(b0 + 1) * V_SZ + v1];
            b.z = x[(u64)(b0 + 2) * V_SZ + v1];
            b.w = x[(u64)(b0 + 3) * V_SZ + v1];
            buf[0][v1] = b;
        }
        pm1_1 = b; pm2_1 = b;
    }
    __syncthreads();

    float4 feat0[5], feat1[5];
#pragma unroll
    for (int f = 0; f < 5; ++f) {
        float w = cws[f * 5];
        feat0[f] = make_float4(w * pm1_0.x, w * pm1_0.y, w * pm1_0.z, w * pm1_0.w);
        feat1[f] = make_float4(w * pm1_1.x, w * pm1_1.y, w * pm1_1.z, w * pm1_1.w);
    }

#pragma unroll
    for (int k = 1; k < KCH; ++k) {
        const float4* prevb = buf[(k - 1) & 1];
        float4*       curb  = buf[k & 1];

        {
            float4 a = make_float4(d0 * pm1_0.x, d0 * pm1_0.y,
                                   d0 * pm1_0.z, d0 * pm1_0.w);
            int4 pw = packed4[t];
            for (int q = 0; q < n0; ++q) {
                int4 pwn = pw;
                if (q + 1 < n0) pwn = packed4[(q + 1) * V_SZ + t];
                float4 g0 = prevb[(u32)pw.x & 1023u];
                float4 g1 = prevb[(u32)pw.y & 1023u];
                float4 g2 = prevb[(u32)pw.z & 1023u];
                float4 g3 = prevb[(u32)pw.w & 1023u];
                float w0 = __uint_as_float((u32)pw.x & 0xFFFFFC00u);
                float w1 = __uint_as_float((u32)pw.y & 0xFFFFFC00u);
                float w2 = __uint_as_float((u32)pw.z & 0xFFFFFC00u);
                float w3 = __uint_as_float((u32)pw.w & 0xFFFFFC00u);
                a.x = fmaf(w0, g0.x, a.x); a.y = fmaf(w0, g0.y, a.y);
                a.z = fmaf(w0, g0.z, a.z); a.w = fmaf(w0, g0.w, a.w);
                a.x = fmaf(w1, g1.x, a.x); a.y = fmaf(w1, g1.y, a.y);
                a.z = fmaf(w1, g1.z, a.z); a.w = fmaf(w1, g1.w, a.w);
                a.x = fmaf(w2, g2.x, a.x); a.y = fmaf(w2, g2.y, a.y);
                a.z = fmaf(w2, g2.z, a.z); a.w = fmaf(w2, g2.w, a.w);
                a.x = fmaf(w3, g3.x, a.x); a.y = fmaf(w3, g3.y, a.y);
                a.z = fmaf(w3, g3.z, a.z); a.w = fmaf(w3, g3.w, a.w);
                pw = pwn;
            }
            if (k >= 2) {
                a.x = fmaf(2.0f, a.x, -pm2_0.x);
                a.y = fmaf(2.0f, a.y, -pm2_0.y);
                a.z = fmaf(2.0f, a.z, -pm2_0.z);
                a.w = fmaf(2.0f, a.w, -pm2_0.w);
            }
            curb[t] = a;
            pm2_0 = pm1_0; pm1_0 = a;
#pragma unroll
            for (int f = 0; f < 5; ++f) {
                float w = cws[f * 5 + k];
                feat0[f].x = fmaf(w, a.x, feat0[f].x);
                feat0[f].y = fmaf(w, a.y, feat0[f].y);
                feat0[f].z = fmaf(w, a.z, feat0[f].z);
                feat0[f].w = fmaf(w, a.w, feat0[f].w);
            }
        }
        if (val1) {
            float4 a = make_float4(d1 * pm1_1.x, d1 * pm1_1.y,
                                   d1 * pm1_1.z, d1 * pm1_1.w);
            int4 pw = packed4[v1];
            for (int q = 0; q < n1; ++q) {
                int4 pwn = pw;
                if (q + 1 < n1) pwn = packed4[(q + 1) * V_SZ + v1];
                float4 g0 = prevb[(u32)pw.x & 1023u];
                float4 g1 = prevb[(u32)pw.y & 1023u];
                float4 g2 = prevb[(u32)pw.z & 1023u];
                float4 g3 = prevb[(u32)pw.w & 1023u];
                float w0 = __uint_as_float((u32)pw.x & 0xFFFFFC00u);
                float w1 = __uint_as_float((u32)pw.y & 0xFFFFFC00u);
                float w2 = __uint_as_float((u32)pw.z & 0xFFFFFC00u);
                float w3 = __uint_as_float((u32)pw.w & 0xFFFFFC00u);
                a.x = fmaf(w0, g0.x, a.x); a.y = fmaf(w0, g0.y, a.y);
                a.z = fmaf(w0, g0.z, a.z); a.w = fmaf(w0, g0.w, a.w);
                a.x = fmaf(w1, g1.x, a.x); a.y = fmaf(w1, g1.y, a.y);
                a.z = fmaf(w1, g1.z, a.z); a.w = fmaf(w1, g1.w, a.w);
                a.x = fmaf(w2, g2.x, a.x); a.y = fmaf(w2, g2.y, a.y);
                a.z = fmaf(w2, g2.z, a.z); a.w = fmaf(w2, g2.w, a.w);
                a.x = fmaf(w3, g3.x, a.x); a.y = fmaf(w3, g3.y, a.y);
                a.z = fmaf(w3, g3.z, a.z); a.w = fmaf(w3, g3.w, a.w);
                pw = pwn;
            }
            if (k >= 2) {
                a.x = fmaf(2.0f, a.x, -pm2_1.x);
                a.y = fmaf(2.0f, a.y, -pm2_1.y);
                a.z = fmaf(2.0f, a.z, -pm2_1.z);
                a.w = fmaf(2.0f, a.w, -pm2_1.w);
            }
            curb[v1] = a;
            pm2_1 = pm1_1; pm1_1 = a;
#pragma unroll
            for (int f = 0; f < 5; ++f) {
                float w = cws[f * 5 + k];
                feat1[f].x = fmaf(w, a.x, feat1[f].x);
                feat1[f].y = fmaf(w, a.y, feat1[f].y);
                feat1[f].z = fmaf(w, a.z, feat1[f].z);
                feat1[f].w = fmaf(w, a.w, feat1[f].w);
            }
        }
        __syncthreads();
    }

#pragma unroll
    for (int f = 0; f < 5; ++f) {
#pragma unroll
        for (int b = 0; b < 4; ++b) {
            float c0 = (b == 0) ? feat0[f].x : (b == 1) ? feat0[f].y
                     : (b == 2) ? feat0[f].z : feat0[f].w;
            float s0 = fmaxf(c0 + cbs[f], 0.0f);
            s0 = fmaxf(s0, __shfl_xor(s0, 1));
            s0 = fmaxf(s0, __shfl_xor(s0, 2));
            s0 = fmaxf(s0, __shfl_xor(s0, 4));
            if ((t & 7) == 0)
                pooled[(u64)(b0 + b) * 640 + (t >> 3) * 5 + f] = f2bf(s0);

            float c1 = (b == 0) ? feat1[f].x : (b == 1) ? feat1[f].y
                     : (b == 2) ? feat1[f].z : feat1[f].w;
            float s1 = val1 ? fmaxf(c1 + cbs[f], 0.0f) : 0.0f;
            s1 = fmaxf(s1, __shfl_xor(s1, 1));
            s1 = fmaxf(s1, __shfl_xor(s1, 2));
            s1 = fmaxf(s1, __shfl_xor(s1, 4));
            if ((t & 7) == 0 && val1)
                pooled[(u64)(b0 + b) * 640 + (v1 >> 3) * 5 + f] = f2bf(s1);
        }
    }
    if (t < 60) {
        int b = t / 15, c = 625 + (t % 15);
        pooled[(u64)(b0 + b) * 640 + c] = 0;
    }
}

// ---------------------------------------------------------------------------
// K2: fused tail. One block = 64 batch rows end-to-end:
//   z  = JKmax(BNx4(relu-chain)) of (pooled[64,640] @ fc1W^T + b)   -> LDS
//   z2 = relu(z @ lin1W^T + b1)                                    -> LDS
//   out= log_softmax(z2 @ l2W^T + b2)                              -> global
// 256 thr (4 waves); wave w owns rows w*16..+16 for ALL phases -> no
// cross-wave LDS hazards on zs. Weights streamed in 64-wide K-tiles via Bs.
// NOTE: Bs indices are TILE-RELATIVE, zs indices ABSOLUTE (round-6 NaN bug:
// using k0+rel for Bs read past the 72-u16 row into w2s -> bf16 NaN patterns).
// ---------------------------------------------------------------------------
__global__ __launch_bounds__(256) void k_tail(const u16* __restrict__ A,      // pooled [B,640]
                                              const u16* __restrict__ W0,     // fc1w_b [256,640]
                                              const float* __restrict__ b0v,  // fc1b
                                              const float* __restrict__ bn_a,
                                              const float* __restrict__ bn_c,
                                              const u16* __restrict__ W1,     // lin1w_b [256,256]
                                              const float* __restrict__ b1v,  // lin1b
                                              const float* __restrict__ W2,   // l2W [10,256] f32
                                              const float* __restrict__ b2v,  // l2b
                                              float* __restrict__ out) {
    __shared__ u16   As[64][72];     // A-tile, +8 pad (stride 36 dw: 2-way free)
    __shared__ u16   Bs[256][72];    // weight K-tile
    __shared__ u16   zs[64][264];    // z / z2, stride 132 dw (=4 mod 32: 2-way)
    __shared__ float w2s[2560];
    __shared__ float b2s[10];
    int t    = threadIdx.x;
    int lane = t & 63;
    int wid  = t >> 6;
    int r0   = blockIdx.x * 64;

    for (int c = t; c < 2560; c += 256) w2s[c] = W2[c];
    if (t < 10) b2s[t] = b2v[t];

    f4v acc[16];
#pragma unroll
    for (int j = 0; j < 16; ++j) acc[j] = (f4v){0.f, 0.f, 0.f, 0.f};

    // ---------------- phase A: z = pooled @ W0^T (K=640) ----------------
    for (int k0 = 0; k0 < 640; k0 += 64) {
        int4 ra[2], rb[8];
#pragma unroll
        for (int i = 0; i < 2; ++i) {
            int c = t + i * 256, row = c >> 3, kc = c & 7;
            ra[i] = *(const int4*)(A + (u64)(r0 + row) * 640 + k0 + kc * 8);
        }
#pragma unroll
        for (int i = 0; i < 8; ++i) {
            int c = t + i * 256, row = c >> 3, kc = c & 7;
            rb[i] = *(const int4*)(W0 + (u64)row * 640 + k0 + kc * 8);
        }
        __syncthreads();   // prior iter's LDS reads done
#pragma unroll
        for (int i = 0; i < 2; ++i) {
            int c = t + i * 256, row = c >> 3, kc = c & 7;
            *(int4*)(&As[row][kc * 8]) = ra[i];
        }
#pragma unroll
        for (int i = 0; i < 8; ++i) {
            int c = t + i * 256, row = c >> 3, kc = c & 7;
            *(int4*)(&Bs[row][kc * 8]) = rb[i];
        }
        __syncthreads();
#pragma unroll
        for (int ks = 0; ks < 2; ++ks) {
            int kq = ks * 32 + (lane >> 4) * 8;
            s8v af = *(const s8v*)(&As[wid * 16 + (lane & 15)][kq]);
#pragma unroll
            for (int nt = 0; nt < 16; ++nt) {
                s8v bf = *(const s8v*)(&Bs[nt * 16 + (lane & 15)][kq]);
                acc[nt] = __builtin_amdgcn_mfma_f32_16x16x32_bf16(af, bf, acc[nt], 0, 0, 0);
            }
        }
    }
    // epilogue A: bias + BNx4(relu) chain + JK max -> zs (own wave band)
#pragma unroll
    for (int nt = 0; nt < 16; ++nt) {
        int col = nt * 16 + (lane & 15);
        float bv = b0v[col];
        float a_[4], c_[4];
#pragma unroll
        for (int i = 0; i < 4; ++i) {
            a_[i] = bn_a[i * 256 + col];
            c_[i] = bn_c[i * 256 + col];
        }
        int rb_ = wid * 16 + (lane >> 4) * 4;
#pragma unroll
        for (int r = 0; r < 4; ++r) {
            float h = acc[nt][r] + bv, z = 0.0f;
#pragma unroll
            for (int i = 0; i < 4; ++i) {
                h = fmaxf(fmaf(a_[i], h, c_[i]), 0.0f);
                z = fmaxf(z, h);
            }
            zs[rb_ + r][col] = f2bf(z);
        }
    }
    __syncthreads();   // zs published; also fences last phase-A Bs reads

    // ---------------- phase B: z2 = relu(z @ W1^T + b1) (K=256) ----------
#pragma unroll
    for (int j = 0; j < 16; ++j) acc[j] = (f4v){0.f, 0.f, 0.f, 0.f};
    for (int k0 = 0; k0 < 256; k0 += 64) {
        int4 rb[8];
#pragma unroll
        for (int i = 0; i < 8; ++i) {
            int c = t + i * 256, row = c >> 3, kc = c & 7;
            rb[i] = *(const int4*)(W1 + (u64)row * 256 + k0 + kc * 8);
        }
        __syncthreads();
#pragma unroll
        for (int i = 0; i < 8; ++i) {
            int c = t + i * 256, row = c >> 3, kc = c & 7;
            *(int4*)(&Bs[row][kc * 8]) = rb[i];
        }
        __syncthreads();
#pragma unroll
        for (int ks = 0; ks < 2; ++ks) {
            int kqr = ks * 32 + (lane >> 4) * 8;        // tile-relative: Bs
            s8v af = *(const s8v*)(&zs[wid * 16 + (lane & 15)][k0 + kqr]);  // absolute: zs
#pragma unroll
            for (int nt = 0; nt < 16; ++nt) {
                s8v bf = *(const s8v*)(&Bs[nt * 16 + (lane & 15)][kqr]);
                acc[nt] = __builtin_amdgcn_mfma_f32_16x16x32_bf16(af, bf, acc[nt], 0, 0, 0);
            }
        }
    }
    // epilogue B: relu -> z2 back into zs (same wave band; in-wave RAW only)
#pragma unroll
    for (int nt = 0; nt < 16; ++nt) {
        int col = nt * 16 + (lane & 15);
        float bv = b1v[col];
        int rb_ = wid * 16 + (lane >> 4) * 4;
#pragma unroll
        for (int r = 0; r < 4; ++r)
            zs[rb_ + r][col] = f2bf(fmaxf(acc[nt][r] + bv, 0.0f));
    }
    __syncthreads();

    // ---------------- phase C: lin2 + log_softmax ------------------------
    // 4 threads per row; thread covers 64 features (32 u32 LDS reads)
    {
        int row = t >> 2, sub = t & 3;
        float a10[10];
#pragma unroll
        for (int o = 0; o < 10; ++o) a10[o] = 0.0f;
        const u32* zrow = (const u32*)(&zs[row][0]);
        for (int kk = sub * 32; kk < sub * 32 + 32; ++kk) {
            u32 pz = zrow[kk];
            float z0 = bf2f((u16)(pz & 0xFFFFu));
            float z1 = bf2f((u16)(pz >> 16));
#pragma unroll
            for (int o = 0; o < 10; ++o) {
                a10[o] = fmaf(z0, w2s[o * 256 + kk * 2], a10[o]);
                a10[o] = fmaf(z1, w2s[o * 256 + kk * 2 + 1], a10[o]);
            }
        }
#pragma unroll
        for (int o = 0; o < 10; ++o) {
            a10[o] += __shfl_xor(a10[o], 1);
            a10[o] += __shfl_xor(a10[o], 2);
        }
        if (sub == 0) {
            float l[10], mx = -1e30f;
#pragma unroll
            for (int o = 0; o < 10; ++o) { l[o] = a10[o] + b2s[o]; mx = fmaxf(mx, l[o]); }
            float s = 0.0f;
#pragma unroll
            for (int o = 0; o < 10; ++o) s += expf(l[o] - mx);
            float ls = logf(s);
            float* orow = out + (u64)(r0 + row) * 10;
#pragma unroll
            for (int o = 0; o < 10; ++o) orow[o] = l[o] - mx - ls;
        }
    }
}

// ---------------------------------------------------------------------------
extern "C" void kernel_launch(void* const* d_in, const int* in_sizes, int n_in,
                              void* d_out, int out_size, void* d_ws, size_t ws_size,
                              hipStream_t stream) {
    const float* x    = (const float*)d_in[0];
    const float* L    = (const float*)d_in[1];
    const float* lmax = (const float*)d_in[2];
    const float* cl1W = (const float*)d_in[3];
    const float* cl1b = (const float*)d_in[4];
    const float* fc1W = (const float*)d_in[5];
    const float* fc1b = (const float*)d_in[6];
    const float* gam  = (const float*)d_in[7];
    const float* bet  = (const float*)d_in[8];
    const float* mea  = (const float*)d_in[9];
    const float* var  = (const float*)d_in[10];
    const float* l1W  = (const float*)d_in[11];
    const float* l1b  = (const float*)d_in[12];
    const float* l2W  = (const float*)d_in[13];
    const float* l2b  = (const float*)d_in[14];

    char* ws = (char*)d_ws;
    u32*   packed  = (u32*)(ws + 0);          // 128000 -> 131072
    int*   cnts    = (int*)(ws + 131072);     // 4096
    float* diagw   = (float*)(ws + 135168);   // 4096
    float* bn_a    = (float*)(ws + 139264);   // 4096
    float* bn_c    = (float*)(ws + 143360);   // 4096
    u16*   fc1w_b  = (u16*)(ws + 147456);     // 327680
    u16*   lin1w_b = (u16*)(ws + 475136);     // 131072
    u16*   pooled  = (u16*)(ws + 606208);     // 10485760
    float* outp    = (float*)d_out;

    k_prep<<<dim3(890), dim3(256), 0, stream>>>(L, lmax, packed, cnts, diagw,
                                                fc1W, l1W, gam, bet, mea, var,
                                                fc1w_b, lin1w_b, bn_a, bn_c);
    k_cheby<<<dim3(2048), dim3(512), 0, stream>>>(x, (const int4*)packed, cnts, diagw,
                                                  cl1W, cl1b, pooled);
    k_tail<<<dim3(128), dim3(256), 0, stream>>>(pooled, fc1w_b, fc1b, bn_a, bn_c,
                                                lin1w_b, l1b, l2W, l2b, outp);
}